// Round 13
// baseline (1444.854 us; speedup 1.0000x reference)
//
#include <hip/hip_runtime.h>
#include <math.h>

// Problem constants (match reference)
#define BB 256
#define NOBJ 100
#define NKEEP 36
#define DD 2048
#define HID 1024
#define KS 256
#define H2 512
#define NP1 (NKEEP + 1)
#define N4H 2048   // 4*H2
#define FDS 8      // f-kernel d-slices (8 blocks/CU -> full occupancy)

typedef __attribute__((ext_vector_type(8))) short short8v;
typedef __attribute__((ext_vector_type(4))) float f32x4;
typedef unsigned short ushort_t;
typedef unsigned int uint_t;

__device__ __forceinline__ float sigf(float x) { return 1.0f / (1.0f + expf(-x)); }
// f32 -> bf16 round-to-nearest-even (bit manip, deterministic)
__device__ __forceinline__ ushort_t f2b(float f) {
  uint_t u = __float_as_uint(f);
  uint_t r = (u + 0x7FFFu + ((u >> 16) & 1u)) >> 16;
  return (ushort_t)r;
}
__device__ __forceinline__ float b2f(ushort_t u) {
  return __uint_as_float(((uint_t)u) << 16);
}
__device__ __forceinline__ short8v pack8(float4 a, float4 b) {
  short8v p;
  p[0] = (short)f2b(a.x); p[1] = (short)f2b(a.y);
  p[2] = (short)f2b(a.z); p[3] = (short)f2b(a.w);
  p[4] = (short)f2b(b.x); p[5] = (short)f2b(b.y);
  p[6] = (short)f2b(b.z); p[7] = (short)f2b(b.w);
  return p;
}

#define GLOAD_LDS16(gp, lp)                                                   \
  __builtin_amdgcn_global_load_lds(                                           \
      (const __attribute__((address_space(1))) void*)(gp),                    \
      (__attribute__((address_space(3))) void*)(lp), 16, 0, 0)

// ---------------------------------------------------------------------------
// K1: per-batch top-NKEEP by attention (stable, descending), gather boxes.
__global__ __launch_bounds__(128) void topk_kernel(
    const float* __restrict__ att, const float* __restrict__ boxes,
    int* __restrict__ idx, float* __restrict__ att_sig,
    float* __restrict__ bxk, int* __restrict__ parent) {
  int b = blockIdx.x;
  int t = threadIdx.x;
  __shared__ float a[NOBJ];
  if (t < NOBJ) a[t] = att[b * NOBJ + t];
  __syncthreads();
  if (t < NOBJ) {
    float ai = a[t];
    int rank = 0;
    for (int j = 0; j < NOBJ; j++) {
      float aj = a[j];
      rank += (aj > ai) || (aj == ai && j < t);
    }
    if (rank < NKEEP) {
      idx[b * NKEEP + rank] = t;
      att_sig[b * NKEEP + rank] = 1.0f / (1.0f + expf(-ai));
      for (int c = 0; c < 4; c++)
        bxk[(b * NKEEP + rank) * 4 + c] = boxes[(b * 4 + c) * NOBJ + t];
    }
  }
  if (t < NKEEP) parent[b * NKEEP + t] = NKEEP;  // sentinel
}

// ---------------------------------------------------------------------------
// K2: gather + split x into A' (fragment-major bf16 [mt][128 ks][g][lane][j]).
// phys ksteps: 0-63 = hi(d), 64-127 = lo(d). 16B vector stores (G13).
__global__ __launch_bounds__(256) void gather_x(
    const float* __restrict__ vf, const int* __restrict__ idx,
    ushort_t* __restrict__ A2) {
  int b = blockIdx.x;
  int ksh = blockIdx.y;       // = d0/32
  int d0 = ksh * 32;
  __shared__ float s[32][101];
  __shared__ int idxs[NKEEP];
  int tid = threadIdx.x;
  if (tid < NKEEP) idxs[tid] = idx[b * NKEEP + tid];
  for (int l = tid; l < 32 * NOBJ; l += 256) {
    int dd = l / NOBJ, c = l % NOBJ;
    s[dd][c] = vf[((size_t)b * DD + d0 + dd) * NOBJ + c];
  }
  __syncthreads();
  if (tid < NKEEP * 4) {
    int n = tid >> 2, q = tid & 3;   // thread owns 8 contiguous frag shorts
    int m = b * NKEEP + n;
    int mt = m >> 7, r = m & 127, g = r >> 4, row16 = r & 15;
    int cix = idxs[n];
    float v[8], lo[8];
#pragma unroll
    for (int j = 0; j < 8; ++j) {
      v[j] = s[q * 8 + j][cix];
      lo[j] = v[j] - b2f(f2b(v[j]));
    }
    float4 va = make_float4(v[0], v[1], v[2], v[3]);
    float4 vb = make_float4(v[4], v[5], v[6], v[7]);
    float4 la = make_float4(lo[0], lo[1], lo[2], lo[3]);
    float4 lb = make_float4(lo[4], lo[5], lo[6], lo[7]);
    size_t base = ((size_t)mt * 128 + ksh) * 4096 + g * 512 + (row16 + q * 16) * 8;
    *(short8v*)&A2[base] = pack8(va, vb);
    *(short8v*)&A2[base + (size_t)64 * 4096] = pack8(la, lb);
  }
}

// ---------------------------------------------------------------------------
// K3a: f partial sums over a 256-wide d-slice. grid (BB, FDS), 256 thr.
__global__ __launch_bounds__(256) void f_partial(
    const float* __restrict__ vo, const float* __restrict__ Wv,
    const int* __restrict__ idx, float* __restrict__ fpart) {
  int b = blockIdx.x;
  int ds = blockIdx.y;
  int k = threadIdx.x;  // 0..255
  __shared__ int idxs[NKEEP];
  __shared__ float vs[16][NKEEP];
  if (k < NKEEP) idxs[k] = idx[b * NKEEP + k];
  __syncthreads();
  float acc[NKEEP];
#pragma unroll
  for (int n = 0; n < NKEEP; n++) acc[n] = 0.0f;
  int dbeg = ds * (DD / FDS);
  for (int d0 = dbeg; d0 < dbeg + DD / FDS; d0 += 16) {
    __syncthreads();
    for (int l = k; l < 16 * NKEEP; l += 256) {
      int dd = l / NKEEP, n = l % NKEEP;
      vs[dd][n] = vo[((size_t)b * DD + d0 + dd) * NOBJ + idxs[n]];
    }
    __syncthreads();
#pragma unroll
    for (int dd = 0; dd < 16; dd++) {
      float w = Wv[(size_t)(d0 + dd) * KS + k];
#pragma unroll
      for (int n = 0; n < NKEEP; n++) acc[n] += vs[dd][n] * w;
    }
  }
  float* op = &fpart[(((size_t)ds * BB + b) * NKEEP) * KS + k];
#pragma unroll
  for (int n = 0; n < NKEEP; n++) op[n * KS] = acc[n];
}

// K3b: combine 8 partials + box term, tanh -> fmat. grid BB, 256 thr.
__global__ __launch_bounds__(256) void f_combine(
    const float* __restrict__ fpart, const float* __restrict__ Wb,
    const float* __restrict__ bxk, float* __restrict__ fmat) {
  int b = blockIdx.x;
  int k = threadIdx.x;
  for (int n = 0; n < NKEEP; n++) {
    float s = 0.0f;
#pragma unroll
    for (int ds = 0; ds < FDS; ds++)
      s += fpart[(((size_t)ds * BB + b) * NKEEP + n) * KS + k];
#pragma unroll
    for (int c = 0; c < 4; c++) s += bxk[(b * NKEEP + n) * 4 + c] * Wb[c * KS + k];
    fmat[((size_t)b * NKEEP + n) * KS + k] = tanhf(s);
  }
}

// ---------------------------------------------------------------------------
// K4: S[b][i][j] = sigmoid((f_i . f_j)/16) * att_i * att_j   (f64 accum)
__global__ __launch_bounds__(256) void s_kernel(
    const float* __restrict__ fmat, const float* __restrict__ att_sig,
    float* __restrict__ S) {
  int b = blockIdx.x;
  int tid = threadIdx.x;
  __shared__ float fs[NKEEP][KS + 1];
  __shared__ float as[NKEEP];
  for (int l = tid; l < NKEEP * KS; l += 256) {
    int n = l / KS, k = l % KS;
    fs[n][k] = fmat[((size_t)b * NKEEP + n) * KS + k];
  }
  if (tid < NKEEP) as[tid] = att_sig[b * NKEEP + tid];
  __syncthreads();
  for (int p = tid; p < NKEEP * NKEEP; p += 256) {
    int i = p / NKEEP, j = p % NKEEP;
    double acc = 0.0;
    for (int k = 0; k < KS; k++) acc += (double)fs[i][k] * (double)fs[j][k];
    float sc = 1.0f / (1.0f + expf(-(float)(acc * (1.0 / 16.0))));
    S[((size_t)b * NKEEP + i) * NKEEP + j] = sc * as[i] * as[j];
  }
}

// ---------------------------------------------------------------------------
// K5: Prim MST forest, one wave per batch.
__global__ __launch_bounds__(64) void prim_kernel(
    const float* __restrict__ S, int* __restrict__ parent,
    int* __restrict__ order) {
  int b = blockIdx.x;
  int lane = threadIdx.x;
  __shared__ float Ss[NKEEP * NKEEP];
  for (int l = lane; l < NKEEP * NKEEP; l += 64) Ss[l] = S[(size_t)b * NKEEP * NKEEP + l];
  __syncthreads();
  unsigned long long mask = 1ull;  // root = 0 (att sorted desc -> argmax=0)
  if (lane == 0) order[b * NKEEP + 0] = 0;
  for (int step = 1; step < NKEEP; step++) {
    float bv = -1.0f;
    int bk = NKEEP * NKEEP;
    for (int l = lane; l < NKEEP * NKEEP; l += 64) {
      int p = l / NKEEP, c = l % NKEEP;
      if (((mask >> p) & 1ull) && !((mask >> c) & 1ull)) {
        float v = Ss[l];
        if (v > bv || (v == bv && l < bk)) { bv = v; bk = l; }
      }
    }
    for (int off = 32; off > 0; off >>= 1) {
      float ov = __shfl_down(bv, off);
      int ok = __shfl_down(bk, off);
      if (ov > bv || (ov == bv && ok < bk)) { bv = ov; bk = ok; }
    }
    bk = __shfl(bk, 0);
    int p = bk / NKEEP, c = bk % NKEEP;
    mask |= (1ull << c);
    if (lane == 0) {
      parent[b * NKEEP + c] = p;
      order[b * NKEEP + step] = c;
    }
  }
}

// ---------------------------------------------------------------------------
// K6a: build W' fragment-major bf16: [nt:32][ks:64][h:8][lane:64][j:8].
// Only HI rows: the hi(A)*lo(B) term is dropped (round-11, verified margin).
__global__ __launch_bounds__(256) void wconv(
    const float* __restrict__ Wu, const float* __restrict__ Wd,
    ushort_t* __restrict__ B2) {
  int nt = blockIdx.x;   // 0..31
  int ks = blockIdx.y;   // 0..63  (hi only)
  int tid = threadIdx.x;
  const float* W = (nt < 16) ? Wu : Wd;
  int n0 = (nt & 15) * 128;
  int k0 = ks * 32;
  __shared__ float tile[32][129];
  for (int l = tid; l < 32 * 128; l += 256) {
    int kk = l >> 7, c = l & 127;
    tile[kk][c] = W[(size_t)(k0 + kk) * N4H + n0 + c];
  }
  __syncthreads();
  size_t obase = ((size_t)nt * 64 + ks) * 4096 + tid * 16;
  ushort_t ob[16];
#pragma unroll
  for (int u = 0; u < 16; u++) {
    int e = tid * 16 + u;
    int h = e >> 9;
    int lane = (e >> 3) & 63;
    int j = e & 7;
    int c = h * 16 + (lane & 15);
    int kk = (lane >> 4) * 8 + j;
    ob[u] = f2b(tile[kk][c]);
  }
  short8v o0, o1;
#pragma unroll
  for (int u = 0; u < 8; ++u) { o0[u] = (short)ob[u]; o1[u] = (short)ob[u + 8]; }
  *(short8v*)&B2[obase] = o0;
  *(short8v*)&B2[obase + 8] = o1;
}

// ---------------------------------------------------------------------------
// K6b: pack Wh (f32 [512][2048]) into frag-major bf16 [s:16][f:128][lane:64][j:8]
__global__ __launch_bounds__(256) void whpack(
    const float* __restrict__ Wh, ushort_t* __restrict__ Wpk) {
  int s = blockIdx.x;      // 0..15
  int fg = blockIdx.y;     // 0..7
  __shared__ float tile[32][257];
  int tid = threadIdx.x;
  for (int l = tid; l < 32 * 64; l += 256) {
    int row = l >> 6, c4 = (l & 63) * 4;
    float4 v = *(const float4*)&Wh[(size_t)(32 * s + row) * N4H + fg * 256 + c4];
    tile[row][c4] = v.x; tile[row][c4 + 1] = v.y;
    tile[row][c4 + 2] = v.z; tile[row][c4 + 3] = v.w;
  }
  __syncthreads();
#pragma unroll
  for (int it = 0; it < 4; it++) {
    int cid = it * 256 + tid;       // 0..1023
    int ff = cid >> 6, lane = cid & 63;
    int f = fg * 16 + ff;
    int col = ff * 16 + (lane & 15);
    int rbase = (lane >> 4) * 8;
    short8v p;
#pragma unroll
    for (int j = 0; j < 8; j++) p[j] = (short)f2b(tile[rbase + j][col]);
    *(short8v*)&Wpk[(((size_t)s * 128 + f) * 64 + lane) * 8] = p;
  }
}

// ---------------------------------------------------------------------------
// K7: MFMA split-bf16 GEMM, 256x128 tile, 2-phase double-buffered.
// 2-term product: A_hi*B_hi + A_lo*B_hi. K'=4096, 128 steps.
// 4 waves, each 64x128 (4 m-frags x 8 n-frags = 32 MFMA per K-step, 12
// ds_read_b128) -> 2x MFMA per barrier vs the 128x128 tile; half the blocks.
// LDS 48KB (A 2x8KB regions + B 8KB, double-buffered); ~200 VGPR -> 2 blk/CU.
__global__ __launch_bounds__(256, 1) void mfma_gemm(
    const ushort_t* __restrict__ A2, const ushort_t* __restrict__ B2,
    const float* __restrict__ bu, const float* __restrict__ bd,
    float* __restrict__ Cu, float* __restrict__ Cd) {
  __shared__ __align__(16) ushort_t Asl[2][8192];  // 16KB/buf: frags 0..15
  __shared__ __align__(16) ushort_t Bsl[2][4096];  // 8KB/buf: frags 0..7
  int bid = blockIdx.x;
  int nt = bid & 31;    // 128-col tile
  int mt2 = bid >> 5;   // 0..35, 256-row tile
  int tid = threadIdx.x;
  int w = tid >> 6, lane = tid & 63;  // w = m-quadrant (64 rows)
  f32x4 acc[4][8];
#pragma unroll
  for (int i = 0; i < 4; i++)
#pragma unroll
    for (int j = 0; j < 8; j++) acc[i][j] = (f32x4){0.f, 0.f, 0.f, 0.f};

  // staging pointers (ushort units; one kstep tile = 4096 ushorts = 8KB)
  const ushort_t* ag0 =
      A2 + (size_t)(2 * mt2) * 128 * 4096 + w * 512 + (size_t)lane * 8;
  const ushort_t* ag1 =
      A2 + (size_t)(2 * mt2 + 1) * 128 * 4096 + w * 512 + (size_t)lane * 8;
  const ushort_t* bgbase =
      B2 + (size_t)nt * 64 * 4096 + w * 512 + (size_t)lane * 8;
  const ushort_t* bg = bgbase;

  auto stage = [&](int hb) {
    // A0 -> Asl[hb][0..4095], A1 -> Asl[hb][4096..8191], B -> Bsl[hb]
    GLOAD_LDS16(ag0, &Asl[hb][w * 512]);
    GLOAD_LDS16(ag0 + 2048, &Asl[hb][2048 + w * 512]);
    GLOAD_LDS16(ag1, &Asl[hb][4096 + w * 512]);
    GLOAD_LDS16(ag1 + 2048, &Asl[hb][4096 + 2048 + w * 512]);
    GLOAD_LDS16(bg, &Bsl[hb][w * 512]);
    GLOAD_LDS16(bg + 2048, &Bsl[hb][2048 + w * 512]);
  };

  stage(0);
  __syncthreads();
  for (int s = 0; s < 128; ++s) {
    int cur = s & 1;
    if (s < 127) {
      ag0 += 4096;                             // A tiles 0..127, no wrap
      ag1 += 4096;
      bg = (s == 63) ? bgbase : bg + 4096;     // B hi tiles wrap once
      stage(cur ^ 1);
    }
    short8v a[4], bfr[8];
#pragma unroll
    for (int mi = 0; mi < 4; mi++)
      a[mi] = *(const short8v*)&Asl[cur][(w * 4 + mi) * 512 + lane * 8];
#pragma unroll
    for (int ni = 0; ni < 8; ni++)
      bfr[ni] = *(const short8v*)&Bsl[cur][ni * 512 + lane * 8];
#pragma unroll
    for (int mi = 0; mi < 4; mi++)
#pragma unroll
      for (int ni = 0; ni < 8; ni++)
        acc[mi][ni] = __builtin_amdgcn_mfma_f32_16x16x32_bf16(
            a[mi], bfr[ni], acc[mi][ni], 0, 0, 0);
    __syncthreads();  // drains vmcnt (next tile staged) + guards buf reuse
  }
  // epilogue: C/D map col=lane&15, row=(lane>>4)*4+reg  [m89-verified]
  int col16 = lane & 15, rq = lane >> 4;
  const float* bias = (nt < 16) ? bu : bd;
  float* C = (nt < 16) ? Cu : Cd;
  int nbase = (nt < 16) ? nt * 128 : nt * 128 - N4H;
#pragma unroll
  for (int ni = 0; ni < 8; ni++) {
    int nn = nbase + ni * 16 + col16;
    float bv = bias[nn];
#pragma unroll
    for (int mi = 0; mi < 4; mi++) {
#pragma unroll
      for (int r = 0; r < 4; r++) {
        int m = mt2 * 256 + w * 64 + mi * 16 + rq * 4 + r;
        C[(size_t)m * N4H + nn] = acc[mi][ni][r] + bv;
      }
    }
  }
}

// ---------------------------------------------------------------------------
// K8: one fused TreeLSTM step (up + dn), 512 blocks x 256 thr (round-6 proven).
__global__ __launch_bounds__(256, 2) void lstm_step(
    int i,
    const float* __restrict__ xWu, const float* __restrict__ xWd,
    const ushort_t* __restrict__ Wpku, const ushort_t* __restrict__ Wpkd,
    const int* __restrict__ order, const int* __restrict__ parent,
    float* __restrict__ hsum, float* __restrict__ csum,
    float* __restrict__ hup, float* __restrict__ hd, float* __restrict__ cd) {
  int bid = blockIdx.x;
  int bt = bid >> 5;
  int pkt = bid & 31;
  bool isdn = pkt >= 16;
  int kt = pkt & 15;
  int t = isdn ? i : (NKEEP - 1 - i);
  const float* xW = isdn ? xWd : xWu;
  const ushort_t* Wpk = isdn ? Wpkd : Wpku;

  __shared__ __align__(16) ushort_t Apk[16 * 64 * 8];  // 16 KB
  __shared__ float pre[16][4][32];                     // 8 KB
  __shared__ int nodes[16], pars[16];

  int tid = threadIdx.x;
  if (tid < 16) {
    int b = bt * 16 + tid;
    int nd = order[b * NKEEP + t];
    nodes[tid] = nd;
    pars[tid] = parent[b * NKEEP + nd];
  }
  __syncthreads();
  // ---- A staging: 16 thr/batch row; thread r covers one s-frag (32 j) ----
  {
    int bl = tid >> 4, r = tid & 15;
    int b = bt * 16 + bl;
    int rowi = isdn ? pars[bl] : nodes[bl];
    const float* asrc = isdn ? &hd[((size_t)b * NP1 + rowi) * H2 + r * 32]
                             : &hsum[((size_t)b * NP1 + rowi) * H2 + r * 32];
    float4 v0 = *(const float4*)&asrc[0];
    float4 v1 = *(const float4*)&asrc[4];
    float4 v2 = *(const float4*)&asrc[8];
    float4 v3 = *(const float4*)&asrc[12];
    float4 v4 = *(const float4*)&asrc[16];
    float4 v5 = *(const float4*)&asrc[20];
    float4 v6 = *(const float4*)&asrc[24];
    float4 v7 = *(const float4*)&asrc[28];
    int x = r & 7;  // XOR swizzle: spreads the r-major stores across banks
    *(short8v*)&Apk[((r * 64 + bl + 0) ^ x) * 8] = pack8(v0, v1);
    *(short8v*)&Apk[((r * 64 + bl + 16) ^ x) * 8] = pack8(v2, v3);
    *(short8v*)&Apk[((r * 64 + bl + 32) ^ x) * 8] = pack8(v4, v5);
    *(short8v*)&Apk[((r * 64 + bl + 48) ^ x) * 8] = pack8(v6, v7);
  }
  __syncthreads();
  // ---- MFMA: wave w = gate; f-pair = g*32 + kt*2 + {0,1} ----
  int w = tid >> 6, lane = tid & 63;
  int col16 = lane & 15, rq = lane >> 4;
  {
    f32x4 acc0 = (f32x4){0.f, 0.f, 0.f, 0.f};
    f32x4 acc1 = (f32x4){0.f, 0.f, 0.f, 0.f};
    int f0 = w * 32 + kt * 2;
#pragma unroll
    for (int s = 0; s < 16; ++s) {
      short8v a = *(const short8v*)&Apk[((s * 64 + lane) ^ (s & 7)) * 8];
      short8v b0 = *(const short8v*)&Wpk[(((size_t)s * 128 + f0) * 64 + lane) * 8];
      short8v b1 = *(const short8v*)&Wpk[(((size_t)s * 128 + f0 + 1) * 64 + lane) * 8];
      acc0 = __builtin_amdgcn_mfma_f32_16x16x32_bf16(a, b0, acc0, 0, 0, 0);
      acc1 = __builtin_amdgcn_mfma_f32_16x16x32_bf16(a, b1, acc1, 0, 0, 0);
    }
#pragma unroll
    for (int r = 0; r < 4; ++r) {
      pre[rq * 4 + r][w][col16] = acc0[r];
      pre[rq * 4 + r][w][16 + col16] = acc1[r];
    }
  }
  __syncthreads();
  // ---- cell epilogue: thread -> (bl, 2 k-cols) ----
  {
    int bl = tid >> 4, kc = (tid & 15) * 2;
    int b = bt * 16 + bl;
    int nd = nodes[bl], pr = pars[bl];
    int k = kt * 32 + kc;
    const float* xwb = &xW[((size_t)b * NKEEP + nd) * N4H + k];
    const float* cpsrc = isdn ? &cd[((size_t)b * NP1 + pr) * H2 + k]
                              : &csum[((size_t)b * NP1 + nd) * H2 + k];
    float2 cp = *(const float2*)cpsrc;
    float hv[2], cv[2];
#pragma unroll
    for (int e = 0; e < 2; ++e) {
      float pi = pre[bl][0][kc + e] + xwb[e];
      float pf = pre[bl][1][kc + e] + xwb[H2 + e];
      float pg = pre[bl][2][kc + e] + xwb[2 * H2 + e];
      float po = pre[bl][3][kc + e] + xwb[3 * H2 + e];
      float cprev = e ? cp.y : cp.x;
      float c = sigf(pi) * tanhf(pg) + sigf(pf) * cprev;
      hv[e] = sigf(po) * tanhf(c);
      cv[e] = c;
    }
    if (!isdn) {
      *(float2*)&hup[((size_t)b * NKEEP + nd) * H2 + k] = make_float2(hv[0], hv[1]);
      float* hsp = &hsum[((size_t)b * NP1 + pr) * H2 + k];
      float* csp = &csum[((size_t)b * NP1 + pr) * H2 + k];
      hsp[0] += hv[0]; hsp[1] += hv[1];
      csp[0] += cv[0]; csp[1] += cv[1];
    } else {
      *(float2*)&hd[((size_t)b * NP1 + nd) * H2 + k] = make_float2(hv[0], hv[1]);
      *(float2*)&cd[((size_t)b * NP1 + nd) * H2 + k] = make_float2(cv[0], cv[1]);
    }
  }
}

// ---------------------------------------------------------------------------
// K9: out[b][q][n] = q<512 ? hup[b][n][q] : hd[b][n][q-512]
__global__ __launch_bounds__(256) void out_transpose(
    const float* __restrict__ hup, const float* __restrict__ hd,
    float* __restrict__ out) {
  int b = blockIdx.x;
  __shared__ float s[NKEEP][65];
  for (int half = 0; half < 2; half++) {
    const float* src = half ? hd : hup;
    int rs = half ? NP1 : NKEEP;
    for (int q0 = 0; q0 < H2; q0 += 64) {
      __syncthreads();
      for (int l = threadIdx.x; l < NKEEP * 64; l += 256) {
        int n = l / 64, qq = l % 64;
        s[n][qq] = src[((size_t)b * rs + n) * H2 + q0 + qq];
      }
      __syncthreads();
      for (int l = threadIdx.x; l < NKEEP * 64; l += 256) {
        int qq = l / NKEEP, n = l % NKEEP;
        out[(size_t)b * (HID * NKEEP) + (half * H2 + q0 + qq) * NKEEP + n] = s[n][qq];
      }
    }
  }
}

// ---------------------------------------------------------------------------
extern "C" void kernel_launch(void* const* d_in, const int* in_sizes, int n_in,
                              void* d_out, int out_size, void* d_ws, size_t ws_size,
                              hipStream_t stream) {
  const float* boxes = (const float*)d_in[0];
  const float* attention = (const float*)d_in[1];
  const float* vf = (const float*)d_in[2];
  const float* vo = (const float*)d_in[3];
  const float* Wv = (const float*)d_in[5];
  const float* Wb = (const float*)d_in[6];
  const float* Wx_up = (const float*)d_in[7];
  const float* Wh_up = (const float*)d_in[8];
  const float* b_up = (const float*)d_in[9];
  const float* Wx_dn = (const float*)d_in[10];
  const float* Wh_dn = (const float*)d_in[11];
  const float* b_dn = (const float*)d_in[12];
  float* out = (float*)d_out;

  char* ws = (char*)d_ws;
  size_t off = 0;
  auto take = [&](size_t bytes) -> char* {
    char* p = ws + off;
    off = (off + bytes + 255) & ~(size_t)255;
    return p;
  };
  int* idx = (int*)take((size_t)BB * NKEEP * 4);
  float* att_sig = (float*)take((size_t)BB * NKEEP * 4);
  float* bxk = (float*)take((size_t)BB * NKEEP * 4 * 4);
  int* parent = (int*)take((size_t)BB * NKEEP * 4);
  int* order = (int*)take((size_t)BB * NKEEP * 4);
  float* fmat = (float*)take((size_t)BB * NKEEP * KS * 4);
  float* S = (float*)take((size_t)BB * NKEEP * NKEEP * 4);
  ushort_t* A2 = (ushort_t*)take((size_t)72 * 128 * 4096 * 2);     // 75.5 MB
  ushort_t* B2 = (ushort_t*)take((size_t)32 * 64 * 4096 * 2);      // 16.8 MB (hi only)
  float* xWu = (float*)take((size_t)BB * NKEEP * N4H * 4);
  float* xWd = (float*)take((size_t)BB * NKEEP * N4H * 4);
  float* hsum = (float*)take((size_t)BB * NP1 * H2 * 4);
  float* csum = (float*)take((size_t)BB * NP1 * H2 * 4);
  float* hd = (float*)take((size_t)BB * NP1 * H2 * 4);
  float* cd = (float*)take((size_t)BB * NP1 * H2 * 4);
  ushort_t* Wpku = (ushort_t*)take((size_t)16 * 128 * 64 * 8 * 2);  // 2 MB
  ushort_t* Wpkd = (ushort_t*)take((size_t)16 * 128 * 64 * 8 * 2);
  float* hup = (float*)A2;    // alias: A2 dead after mfma_gemm
  float* fpart = xWd;         // alias: consumed by f_combine before gemm writes

  topk_kernel<<<BB, 128, 0, stream>>>(attention, boxes, idx, att_sig, bxk, parent);
  gather_x<<<dim3(BB, 64), 256, 0, stream>>>(vf, idx, A2);
  f_partial<<<dim3(BB, FDS), 256, 0, stream>>>(vo, Wv, idx, fpart);
  f_combine<<<BB, 256, 0, stream>>>(fpart, Wb, bxk, fmat);
  s_kernel<<<BB, 256, 0, stream>>>(fmat, att_sig, S);
  prim_kernel<<<BB, 64, 0, stream>>>(S, parent, order);

  wconv<<<dim3(32, 64), 256, 0, stream>>>(Wx_up, Wx_dn, B2);
  whpack<<<dim3(16, 8), 256, 0, stream>>>(Wh_up, Wpku);
  whpack<<<dim3(16, 8), 256, 0, stream>>>(Wh_dn, Wpkd);

  // 256x128-tile GEMM: 36 m-tiles x 32 n-tiles = 1152 blocks
  mfma_gemm<<<36 * 32, 256, 0, stream>>>(A2, B2, b_up, b_dn, xWu, xWd);

  size_t accb = (size_t)BB * NP1 * H2 * 4;
  hipMemsetAsync(hsum, 0, accb * 4, stream);  // hsum,csum,hd,cd contiguous

  for (int i = 0; i < NKEEP; ++i)
    lstm_step<<<512, 256, 0, stream>>>(i, xWu, xWd, Wpku, Wpkd, order, parent,
                                       hsum, csum, hup, hd, cd);

  out_transpose<<<BB, 256, 0, stream>>>(hup, hd, out);
}

// Round 14
// 1218.004 us; speedup vs baseline: 1.1862x; 1.1862x over previous
//
#include <hip/hip_runtime.h>
#include <math.h>

// Problem constants (match reference)
#define BB 256
#define NOBJ 100
#define NKEEP 36
#define DD 2048
#define HID 1024
#define KS 256
#define H2 512
#define NP1 (NKEEP + 1)
#define N4H 2048   // 4*H2
#define FDS 8      // f-kernel d-slices (8 blocks/CU -> full occupancy)

typedef __attribute__((ext_vector_type(8))) short short8v;
typedef __attribute__((ext_vector_type(4))) float f32x4;
typedef unsigned short ushort_t;
typedef unsigned int uint_t;

__device__ __forceinline__ float sigf(float x) { return 1.0f / (1.0f + expf(-x)); }
// f32 -> bf16 round-to-nearest-even (bit manip, deterministic)
__device__ __forceinline__ ushort_t f2b(float f) {
  uint_t u = __float_as_uint(f);
  uint_t r = (u + 0x7FFFu + ((u >> 16) & 1u)) >> 16;
  return (ushort_t)r;
}
__device__ __forceinline__ float b2f(ushort_t u) {
  return __uint_as_float(((uint_t)u) << 16);
}
__device__ __forceinline__ short8v pack8(float4 a, float4 b) {
  short8v p;
  p[0] = (short)f2b(a.x); p[1] = (short)f2b(a.y);
  p[2] = (short)f2b(a.z); p[3] = (short)f2b(a.w);
  p[4] = (short)f2b(b.x); p[5] = (short)f2b(b.y);
  p[6] = (short)f2b(b.z); p[7] = (short)f2b(b.w);
  return p;
}

#define GLOAD_LDS16(gp, lp)                                                   \
  __builtin_amdgcn_global_load_lds(                                           \
      (const __attribute__((address_space(1))) void*)(gp),                    \
      (__attribute__((address_space(3))) void*)(lp), 16, 0, 0)

// ---------------------------------------------------------------------------
// K1: per-batch top-NKEEP by attention (stable, descending), gather boxes.
__global__ __launch_bounds__(128) void topk_kernel(
    const float* __restrict__ att, const float* __restrict__ boxes,
    int* __restrict__ idx, float* __restrict__ att_sig,
    float* __restrict__ bxk, int* __restrict__ parent) {
  int b = blockIdx.x;
  int t = threadIdx.x;
  __shared__ float a[NOBJ];
  if (t < NOBJ) a[t] = att[b * NOBJ + t];
  __syncthreads();
  if (t < NOBJ) {
    float ai = a[t];
    int rank = 0;
    for (int j = 0; j < NOBJ; j++) {
      float aj = a[j];
      rank += (aj > ai) || (aj == ai && j < t);
    }
    if (rank < NKEEP) {
      idx[b * NKEEP + rank] = t;
      att_sig[b * NKEEP + rank] = 1.0f / (1.0f + expf(-ai));
      for (int c = 0; c < 4; c++)
        bxk[(b * NKEEP + rank) * 4 + c] = boxes[(b * 4 + c) * NOBJ + t];
    }
  }
  if (t < NKEEP) parent[b * NKEEP + t] = NKEEP;  // sentinel
}

// ---------------------------------------------------------------------------
// K2: gather + split x into A' (fragment-major bf16 [mt][128 ks][g][lane][j]).
// phys ksteps: 0-63 = hi(d), 64-127 = lo(d). 16B vector stores (G13).
__global__ __launch_bounds__(256) void gather_x(
    const float* __restrict__ vf, const int* __restrict__ idx,
    ushort_t* __restrict__ A2) {
  int b = blockIdx.x;
  int ksh = blockIdx.y;       // = d0/32
  int d0 = ksh * 32;
  __shared__ float s[32][101];
  __shared__ int idxs[NKEEP];
  int tid = threadIdx.x;
  if (tid < NKEEP) idxs[tid] = idx[b * NKEEP + tid];
  for (int l = tid; l < 32 * NOBJ; l += 256) {
    int dd = l / NOBJ, c = l % NOBJ;
    s[dd][c] = vf[((size_t)b * DD + d0 + dd) * NOBJ + c];
  }
  __syncthreads();
  if (tid < NKEEP * 4) {
    int n = tid >> 2, q = tid & 3;   // thread owns 8 contiguous frag shorts
    int m = b * NKEEP + n;
    int mt = m >> 7, r = m & 127, g = r >> 4, row16 = r & 15;
    int cix = idxs[n];
    float v[8], lo[8];
#pragma unroll
    for (int j = 0; j < 8; ++j) {
      v[j] = s[q * 8 + j][cix];
      lo[j] = v[j] - b2f(f2b(v[j]));
    }
    float4 va = make_float4(v[0], v[1], v[2], v[3]);
    float4 vb = make_float4(v[4], v[5], v[6], v[7]);
    float4 la = make_float4(lo[0], lo[1], lo[2], lo[3]);
    float4 lb = make_float4(lo[4], lo[5], lo[6], lo[7]);
    size_t base = ((size_t)mt * 128 + ksh) * 4096 + g * 512 + (row16 + q * 16) * 8;
    *(short8v*)&A2[base] = pack8(va, vb);
    *(short8v*)&A2[base + (size_t)64 * 4096] = pack8(la, lb);
  }
}

// ---------------------------------------------------------------------------
// K3a: f partial sums over a 256-wide d-slice. grid (BB, FDS), 256 thr.
__global__ __launch_bounds__(256) void f_partial(
    const float* __restrict__ vo, const float* __restrict__ Wv,
    const int* __restrict__ idx, float* __restrict__ fpart) {
  int b = blockIdx.x;
  int ds = blockIdx.y;
  int k = threadIdx.x;  // 0..255
  __shared__ int idxs[NKEEP];
  __shared__ float vs[16][NKEEP];
  if (k < NKEEP) idxs[k] = idx[b * NKEEP + k];
  __syncthreads();
  float acc[NKEEP];
#pragma unroll
  for (int n = 0; n < NKEEP; n++) acc[n] = 0.0f;
  int dbeg = ds * (DD / FDS);
  for (int d0 = dbeg; d0 < dbeg + DD / FDS; d0 += 16) {
    __syncthreads();
    for (int l = k; l < 16 * NKEEP; l += 256) {
      int dd = l / NKEEP, n = l % NKEEP;
      vs[dd][n] = vo[((size_t)b * DD + d0 + dd) * NOBJ + idxs[n]];
    }
    __syncthreads();
#pragma unroll
    for (int dd = 0; dd < 16; dd++) {
      float w = Wv[(size_t)(d0 + dd) * KS + k];
#pragma unroll
      for (int n = 0; n < NKEEP; n++) acc[n] += vs[dd][n] * w;
    }
  }
  float* op = &fpart[(((size_t)ds * BB + b) * NKEEP) * KS + k];
#pragma unroll
  for (int n = 0; n < NKEEP; n++) op[n * KS] = acc[n];
}

// K3b: combine 8 partials + box term, tanh -> fmat. grid BB, 256 thr.
__global__ __launch_bounds__(256) void f_combine(
    const float* __restrict__ fpart, const float* __restrict__ Wb,
    const float* __restrict__ bxk, float* __restrict__ fmat) {
  int b = blockIdx.x;
  int k = threadIdx.x;
  for (int n = 0; n < NKEEP; n++) {
    float s = 0.0f;
#pragma unroll
    for (int ds = 0; ds < FDS; ds++)
      s += fpart[(((size_t)ds * BB + b) * NKEEP + n) * KS + k];
#pragma unroll
    for (int c = 0; c < 4; c++) s += bxk[(b * NKEEP + n) * 4 + c] * Wb[c * KS + k];
    fmat[((size_t)b * NKEEP + n) * KS + k] = tanhf(s);
  }
}

// ---------------------------------------------------------------------------
// K4: S[b][i][j] = sigmoid((f_i . f_j)/16) * att_i * att_j   (f64 accum)
__global__ __launch_bounds__(256) void s_kernel(
    const float* __restrict__ fmat, const float* __restrict__ att_sig,
    float* __restrict__ S) {
  int b = blockIdx.x;
  int tid = threadIdx.x;
  __shared__ float fs[NKEEP][KS + 1];
  __shared__ float as[NKEEP];
  for (int l = tid; l < NKEEP * KS; l += 256) {
    int n = l / KS, k = l % KS;
    fs[n][k] = fmat[((size_t)b * NKEEP + n) * KS + k];
  }
  if (tid < NKEEP) as[tid] = att_sig[b * NKEEP + tid];
  __syncthreads();
  for (int p = tid; p < NKEEP * NKEEP; p += 256) {
    int i = p / NKEEP, j = p % NKEEP;
    double acc = 0.0;
    for (int k = 0; k < KS; k++) acc += (double)fs[i][k] * (double)fs[j][k];
    float sc = 1.0f / (1.0f + expf(-(float)(acc * (1.0 / 16.0))));
    S[((size_t)b * NKEEP + i) * NKEEP + j] = sc * as[i] * as[j];
  }
}

// ---------------------------------------------------------------------------
// K5: Prim MST forest, one wave per batch.
__global__ __launch_bounds__(64) void prim_kernel(
    const float* __restrict__ S, int* __restrict__ parent,
    int* __restrict__ order) {
  int b = blockIdx.x;
  int lane = threadIdx.x;
  __shared__ float Ss[NKEEP * NKEEP];
  for (int l = lane; l < NKEEP * NKEEP; l += 64) Ss[l] = S[(size_t)b * NKEEP * NKEEP + l];
  __syncthreads();
  unsigned long long mask = 1ull;  // root = 0 (att sorted desc -> argmax=0)
  if (lane == 0) order[b * NKEEP + 0] = 0;
  for (int step = 1; step < NKEEP; step++) {
    float bv = -1.0f;
    int bk = NKEEP * NKEEP;
    for (int l = lane; l < NKEEP * NKEEP; l += 64) {
      int p = l / NKEEP, c = l % NKEEP;
      if (((mask >> p) & 1ull) && !((mask >> c) & 1ull)) {
        float v = Ss[l];
        if (v > bv || (v == bv && l < bk)) { bv = v; bk = l; }
      }
    }
    for (int off = 32; off > 0; off >>= 1) {
      float ov = __shfl_down(bv, off);
      int ok = __shfl_down(bk, off);
      if (ov > bv || (ov == bv && ok < bk)) { bv = ov; bk = ok; }
    }
    bk = __shfl(bk, 0);
    int p = bk / NKEEP, c = bk % NKEEP;
    mask |= (1ull << c);
    if (lane == 0) {
      parent[b * NKEEP + c] = p;
      order[b * NKEEP + step] = c;
    }
  }
}

// ---------------------------------------------------------------------------
// K6a: build W' fragment-major bf16: [nt:32][ks:64][h:8][lane:64][j:8].
// Only HI rows: the hi(A)*lo(B) term is dropped (round-11, verified margin).
__global__ __launch_bounds__(256) void wconv(
    const float* __restrict__ Wu, const float* __restrict__ Wd,
    ushort_t* __restrict__ B2) {
  int nt = blockIdx.x;   // 0..31
  int ks = blockIdx.y;   // 0..63  (hi only)
  int tid = threadIdx.x;
  const float* W = (nt < 16) ? Wu : Wd;
  int n0 = (nt & 15) * 128;
  int k0 = ks * 32;
  __shared__ float tile[32][129];
  for (int l = tid; l < 32 * 128; l += 256) {
    int kk = l >> 7, c = l & 127;
    tile[kk][c] = W[(size_t)(k0 + kk) * N4H + n0 + c];
  }
  __syncthreads();
  size_t obase = ((size_t)nt * 64 + ks) * 4096 + tid * 16;
  ushort_t ob[16];
#pragma unroll
  for (int u = 0; u < 16; u++) {
    int e = tid * 16 + u;
    int h = e >> 9;
    int lane = (e >> 3) & 63;
    int j = e & 7;
    int c = h * 16 + (lane & 15);
    int kk = (lane >> 4) * 8 + j;
    ob[u] = f2b(tile[kk][c]);
  }
  short8v o0, o1;
#pragma unroll
  for (int u = 0; u < 8; ++u) { o0[u] = (short)ob[u]; o1[u] = (short)ob[u + 8]; }
  *(short8v*)&B2[obase] = o0;
  *(short8v*)&B2[obase + 8] = o1;
}

// ---------------------------------------------------------------------------
// K6b: pack Wh (f32 [512][2048]) into frag-major bf16 [s:16][f:128][lane:64][j:8]
__global__ __launch_bounds__(256) void whpack(
    const float* __restrict__ Wh, ushort_t* __restrict__ Wpk) {
  int s = blockIdx.x;      // 0..15
  int fg = blockIdx.y;     // 0..7
  __shared__ float tile[32][257];
  int tid = threadIdx.x;
  for (int l = tid; l < 32 * 64; l += 256) {
    int row = l >> 6, c4 = (l & 63) * 4;
    float4 v = *(const float4*)&Wh[(size_t)(32 * s + row) * N4H + fg * 256 + c4];
    tile[row][c4] = v.x; tile[row][c4 + 1] = v.y;
    tile[row][c4 + 2] = v.z; tile[row][c4 + 3] = v.w;
  }
  __syncthreads();
#pragma unroll
  for (int it = 0; it < 4; it++) {
    int cid = it * 256 + tid;       // 0..1023
    int ff = cid >> 6, lane = cid & 63;
    int f = fg * 16 + ff;
    int col = ff * 16 + (lane & 15);
    int rbase = (lane >> 4) * 8;
    short8v p;
#pragma unroll
    for (int j = 0; j < 8; j++) p[j] = (short)f2b(tile[rbase + j][col]);
    *(short8v*)&Wpk[(((size_t)s * 128 + f) * 64 + lane) * 8] = p;
  }
}

// ---------------------------------------------------------------------------
// K7: MFMA split-bf16 GEMM, 128x128 tile, 2-phase double-buffered,
// incremental staging pointers (round-12 proven: 401us, MfmaUtil 35.6%).
// 2-term product: A_hi*B_hi + A_lo*B_hi. K'=4096, 128 steps.
// NOTE round-13 lesson: 256x128 tile REGRESSED (640us, MfmaUtil 20%) —
// bigger tiles need the 8-phase counted-vmcnt schedule; with a simple
// 2-barrier loop, 128^2 + high co-residency wins (guide §5 tile-space).
__global__ __launch_bounds__(256) void mfma_gemm(
    const ushort_t* __restrict__ A2, const ushort_t* __restrict__ B2,
    const float* __restrict__ bu, const float* __restrict__ bd,
    float* __restrict__ Cu, float* __restrict__ Cd) {
  __shared__ __align__(16) ushort_t Asl[2][4096];
  __shared__ __align__(16) ushort_t Bsl[2][4096];
  int bid = blockIdx.x;
  int nt = bid & 31;
  int mt = bid >> 5;
  int tid = threadIdx.x;
  int w = tid >> 6, lane = tid & 63;
  int wr = w >> 1, wc = w & 1;
  f32x4 acc[4][4];
#pragma unroll
  for (int i = 0; i < 4; i++)
#pragma unroll
    for (int j = 0; j < 4; j++) acc[i][j] = (f32x4){0.f, 0.f, 0.f, 0.f};

  const ushort_t* ag =
      A2 + (size_t)mt * 128 * 4096 + (w * 2) * 512 + (size_t)lane * 8;
  const ushort_t* bgbase =
      B2 + (size_t)nt * 64 * 4096 + (w * 2) * 512 + (size_t)lane * 8;
  const ushort_t* bg = bgbase;
  ushort_t* as0 = &Asl[0][(w * 2) * 512];
  ushort_t* bs0 = &Bsl[0][(w * 2) * 512];
  ushort_t* as1 = &Asl[1][(w * 2) * 512];
  ushort_t* bs1 = &Bsl[1][(w * 2) * 512];

  GLOAD_LDS16(ag, as0);
  GLOAD_LDS16(ag + 512, as0 + 512);
  GLOAD_LDS16(bg, bs0);
  GLOAD_LDS16(bg + 512, bs0 + 512);
  __syncthreads();
  for (int s = 0; s < 128; ++s) {
    int cur = s & 1;
    if (s < 127) {
      ag += 4096;                              // A tiles 0..127, no wrap
      bg = (s == 63) ? bgbase : bg + 4096;     // B hi tiles wrap once
      ushort_t* asd = cur ? as0 : as1;
      ushort_t* bsd = cur ? bs0 : bs1;
      GLOAD_LDS16(ag, asd);
      GLOAD_LDS16(ag + 512, asd + 512);
      GLOAD_LDS16(bg, bsd);
      GLOAD_LDS16(bg + 512, bsd + 512);
    }
    short8v a[4], bfr[4];
#pragma unroll
    for (int mi = 0; mi < 4; mi++)
      a[mi] = *(const short8v*)&Asl[cur][(wr * 4 + mi) * 512 + lane * 8];
#pragma unroll
    for (int ni = 0; ni < 4; ni++)
      bfr[ni] = *(const short8v*)&Bsl[cur][(wc * 4 + ni) * 512 + lane * 8];
#pragma unroll
    for (int mi = 0; mi < 4; mi++)
#pragma unroll
      for (int ni = 0; ni < 4; ni++)
        acc[mi][ni] = __builtin_amdgcn_mfma_f32_16x16x32_bf16(
            a[mi], bfr[ni], acc[mi][ni], 0, 0, 0);
    __syncthreads();  // drains vmcnt (next tile staged) + guards buf reuse
  }
  // epilogue: C/D map col=lane&15, row=(lane>>4)*4+reg  [m89-verified]
  int col16 = lane & 15, rq = lane >> 4;
#pragma unroll
  for (int ni = 0; ni < 4; ni++) {
    int nglob = nt * 128 + wc * 64 + ni * 16 + col16;
    const float* bias = (nt < 16) ? bu : bd;
    float* C = (nt < 16) ? Cu : Cd;
    int nn = (nt < 16) ? nglob : nglob - N4H;
    float bv = bias[nn];
#pragma unroll
    for (int mi = 0; mi < 4; mi++) {
#pragma unroll
      for (int r = 0; r < 4; r++) {
        int m = mt * 128 + wr * 64 + mi * 16 + rq * 4 + r;
        C[(size_t)m * N4H + nn] = acc[mi][ni][r] + bv;
      }
    }
  }
}

// ---------------------------------------------------------------------------
// K8: one fused TreeLSTM step (up + dn), 512 blocks x 256 thr (round-6 proven).
__global__ __launch_bounds__(256, 2) void lstm_step(
    int i,
    const float* __restrict__ xWu, const float* __restrict__ xWd,
    const ushort_t* __restrict__ Wpku, const ushort_t* __restrict__ Wpkd,
    const int* __restrict__ order, const int* __restrict__ parent,
    float* __restrict__ hsum, float* __restrict__ csum,
    float* __restrict__ hup, float* __restrict__ hd, float* __restrict__ cd) {
  int bid = blockIdx.x;
  int bt = bid >> 5;
  int pkt = bid & 31;
  bool isdn = pkt >= 16;
  int kt = pkt & 15;
  int t = isdn ? i : (NKEEP - 1 - i);
  const float* xW = isdn ? xWd : xWu;
  const ushort_t* Wpk = isdn ? Wpkd : Wpku;

  __shared__ __align__(16) ushort_t Apk[16 * 64 * 8];  // 16 KB
  __shared__ float pre[16][4][32];                     // 8 KB
  __shared__ int nodes[16], pars[16];

  int tid = threadIdx.x;
  if (tid < 16) {
    int b = bt * 16 + tid;
    int nd = order[b * NKEEP + t];
    nodes[tid] = nd;
    pars[tid] = parent[b * NKEEP + nd];
  }
  __syncthreads();
  // ---- A staging: 16 thr/batch row; thread r covers one s-frag (32 j) ----
  {
    int bl = tid >> 4, r = tid & 15;
    int b = bt * 16 + bl;
    int rowi = isdn ? pars[bl] : nodes[bl];
    const float* asrc = isdn ? &hd[((size_t)b * NP1 + rowi) * H2 + r * 32]
                             : &hsum[((size_t)b * NP1 + rowi) * H2 + r * 32];
    float4 v0 = *(const float4*)&asrc[0];
    float4 v1 = *(const float4*)&asrc[4];
    float4 v2 = *(const float4*)&asrc[8];
    float4 v3 = *(const float4*)&asrc[12];
    float4 v4 = *(const float4*)&asrc[16];
    float4 v5 = *(const float4*)&asrc[20];
    float4 v6 = *(const float4*)&asrc[24];
    float4 v7 = *(const float4*)&asrc[28];
    int x = r & 7;  // XOR swizzle: spreads the r-major stores across banks
    *(short8v*)&Apk[((r * 64 + bl + 0) ^ x) * 8] = pack8(v0, v1);
    *(short8v*)&Apk[((r * 64 + bl + 16) ^ x) * 8] = pack8(v2, v3);
    *(short8v*)&Apk[((r * 64 + bl + 32) ^ x) * 8] = pack8(v4, v5);
    *(short8v*)&Apk[((r * 64 + bl + 48) ^ x) * 8] = pack8(v6, v7);
  }
  __syncthreads();
  // ---- MFMA: wave w = gate; f-pair = g*32 + kt*2 + {0,1} ----
  int w = tid >> 6, lane = tid & 63;
  int col16 = lane & 15, rq = lane >> 4;
  {
    f32x4 acc0 = (f32x4){0.f, 0.f, 0.f, 0.f};
    f32x4 acc1 = (f32x4){0.f, 0.f, 0.f, 0.f};
    int f0 = w * 32 + kt * 2;
#pragma unroll
    for (int s = 0; s < 16; ++s) {
      short8v a = *(const short8v*)&Apk[((s * 64 + lane) ^ (s & 7)) * 8];
      short8v b0 = *(const short8v*)&Wpk[(((size_t)s * 128 + f0) * 64 + lane) * 8];
      short8v b1 = *(const short8v*)&Wpk[(((size_t)s * 128 + f0 + 1) * 64 + lane) * 8];
      acc0 = __builtin_amdgcn_mfma_f32_16x16x32_bf16(a, b0, acc0, 0, 0, 0);
      acc1 = __builtin_amdgcn_mfma_f32_16x16x32_bf16(a, b1, acc1, 0, 0, 0);
    }
#pragma unroll
    for (int r = 0; r < 4; ++r) {
      pre[rq * 4 + r][w][col16] = acc0[r];
      pre[rq * 4 + r][w][16 + col16] = acc1[r];
    }
  }
  __syncthreads();
  // ---- cell epilogue: thread -> (bl, 2 k-cols) ----
  {
    int bl = tid >> 4, kc = (tid & 15) * 2;
    int b = bt * 16 + bl;
    int nd = nodes[bl], pr = pars[bl];
    int k = kt * 32 + kc;
    const float* xwb = &xW[((size_t)b * NKEEP + nd) * N4H + k];
    const float* cpsrc = isdn ? &cd[((size_t)b * NP1 + pr) * H2 + k]
                              : &csum[((size_t)b * NP1 + nd) * H2 + k];
    float2 cp = *(const float2*)cpsrc;
    float hv[2], cv[2];
#pragma unroll
    for (int e = 0; e < 2; ++e) {
      float pi = pre[bl][0][kc + e] + xwb[e];
      float pf = pre[bl][1][kc + e] + xwb[H2 + e];
      float pg = pre[bl][2][kc + e] + xwb[2 * H2 + e];
      float po = pre[bl][3][kc + e] + xwb[3 * H2 + e];
      float cprev = e ? cp.y : cp.x;
      float c = sigf(pi) * tanhf(pg) + sigf(pf) * cprev;
      hv[e] = sigf(po) * tanhf(c);
      cv[e] = c;
    }
    if (!isdn) {
      *(float2*)&hup[((size_t)b * NKEEP + nd) * H2 + k] = make_float2(hv[0], hv[1]);
      float* hsp = &hsum[((size_t)b * NP1 + pr) * H2 + k];
      float* csp = &csum[((size_t)b * NP1 + pr) * H2 + k];
      hsp[0] += hv[0]; hsp[1] += hv[1];
      csp[0] += cv[0]; csp[1] += cv[1];
    } else {
      *(float2*)&hd[((size_t)b * NP1 + nd) * H2 + k] = make_float2(hv[0], hv[1]);
      *(float2*)&cd[((size_t)b * NP1 + nd) * H2 + k] = make_float2(cv[0], cv[1]);
    }
  }
}

// ---------------------------------------------------------------------------
// K9: out[b][q][n] = q<512 ? hup[b][n][q] : hd[b][n][q-512]
__global__ __launch_bounds__(256) void out_transpose(
    const float* __restrict__ hup, const float* __restrict__ hd,
    float* __restrict__ out) {
  int b = blockIdx.x;
  __shared__ float s[NKEEP][65];
  for (int half = 0; half < 2; half++) {
    const float* src = half ? hd : hup;
    int rs = half ? NP1 : NKEEP;
    for (int q0 = 0; q0 < H2; q0 += 64) {
      __syncthreads();
      for (int l = threadIdx.x; l < NKEEP * 64; l += 256) {
        int n = l / 64, qq = l % 64;
        s[n][qq] = src[((size_t)b * rs + n) * H2 + q0 + qq];
      }
      __syncthreads();
      for (int l = threadIdx.x; l < NKEEP * 64; l += 256) {
        int qq = l / NKEEP, n = l % NKEEP;
        out[(size_t)b * (HID * NKEEP) + (half * H2 + q0 + qq) * NKEEP + n] = s[n][qq];
      }
    }
  }
}

// ---------------------------------------------------------------------------
extern "C" void kernel_launch(void* const* d_in, const int* in_sizes, int n_in,
                              void* d_out, int out_size, void* d_ws, size_t ws_size,
                              hipStream_t stream) {
  const float* boxes = (const float*)d_in[0];
  const float* attention = (const float*)d_in[1];
  const float* vf = (const float*)d_in[2];
  const float* vo = (const float*)d_in[3];
  const float* Wv = (const float*)d_in[5];
  const float* Wb = (const float*)d_in[6];
  const float* Wx_up = (const float*)d_in[7];
  const float* Wh_up = (const float*)d_in[8];
  const float* b_up = (const float*)d_in[9];
  const float* Wx_dn = (const float*)d_in[10];
  const float* Wh_dn = (const float*)d_in[11];
  const float* b_dn = (const float*)d_in[12];
  float* out = (float*)d_out;

  char* ws = (char*)d_ws;
  size_t off = 0;
  auto take = [&](size_t bytes) -> char* {
    char* p = ws + off;
    off = (off + bytes + 255) & ~(size_t)255;
    return p;
  };
  int* idx = (int*)take((size_t)BB * NKEEP * 4);
  float* att_sig = (float*)take((size_t)BB * NKEEP * 4);
  float* bxk = (float*)take((size_t)BB * NKEEP * 4 * 4);
  int* parent = (int*)take((size_t)BB * NKEEP * 4);
  int* order = (int*)take((size_t)BB * NKEEP * 4);
  float* fmat = (float*)take((size_t)BB * NKEEP * KS * 4);
  float* S = (float*)take((size_t)BB * NKEEP * NKEEP * 4);
  ushort_t* A2 = (ushort_t*)take((size_t)72 * 128 * 4096 * 2);     // 75.5 MB
  ushort_t* B2 = (ushort_t*)take((size_t)32 * 64 * 4096 * 2);      // 16.8 MB (hi only)
  float* xWu = (float*)take((size_t)BB * NKEEP * N4H * 4);
  float* xWd = (float*)take((size_t)BB * NKEEP * N4H * 4);
  float* hsum = (float*)take((size_t)BB * NP1 * H2 * 4);
  float* csum = (float*)take((size_t)BB * NP1 * H2 * 4);
  float* hd = (float*)take((size_t)BB * NP1 * H2 * 4);
  float* cd = (float*)take((size_t)BB * NP1 * H2 * 4);
  ushort_t* Wpku = (ushort_t*)take((size_t)16 * 128 * 64 * 8 * 2);  // 2 MB
  ushort_t* Wpkd = (ushort_t*)take((size_t)16 * 128 * 64 * 8 * 2);
  float* hup = (float*)A2;    // alias: A2 dead after mfma_gemm
  float* fpart = xWd;         // alias: consumed by f_combine before gemm writes

  topk_kernel<<<BB, 128, 0, stream>>>(attention, boxes, idx, att_sig, bxk, parent);
  gather_x<<<dim3(BB, 64), 256, 0, stream>>>(vf, idx, A2);
  f_partial<<<dim3(BB, FDS), 256, 0, stream>>>(vo, Wv, idx, fpart);
  f_combine<<<BB, 256, 0, stream>>>(fpart, Wb, bxk, fmat);
  s_kernel<<<BB, 256, 0, stream>>>(fmat, att_sig, S);
  prim_kernel<<<BB, 64, 0, stream>>>(S, parent, order);

  wconv<<<dim3(32, 64), 256, 0, stream>>>(Wx_up, Wx_dn, B2);
  whpack<<<dim3(16, 8), 256, 0, stream>>>(Wh_up, Wpku);
  whpack<<<dim3(16, 8), 256, 0, stream>>>(Wh_dn, Wpkd);

  mfma_gemm<<<72 * 32, 256, 0, stream>>>(A2, B2, b_up, b_dn, xWu, xWd);

  size_t accb = (size_t)BB * NP1 * H2 * 4;
  hipMemsetAsync(hsum, 0, accb * 4, stream);  // hsum,csum,hd,cd contiguous

  for (int i = 0; i < NKEEP; ++i)
    lstm_step<<<512, 256, 0, stream>>>(i, xWu, xWd, Wpku, Wpkd, order, parent,
                                       hsum, csum, hup, hd, cd);

  out_transpose<<<BB, 256, 0, stream>>>(hup, hd, out);
}

// Round 15
// 1007.703 us; speedup vs baseline: 1.4338x; 1.2087x over previous
//
#include <hip/hip_runtime.h>
#include <math.h>

// Problem constants (match reference)
#define BB 256
#define NOBJ 100
#define NKEEP 36
#define DD 2048
#define HID 1024
#define KS 256
#define H2 512
#define NP1 (NKEEP + 1)
#define N4H 2048   // 4*H2
#define FDS 8      // f-kernel d-slices (8 blocks/CU -> full occupancy)

typedef __attribute__((ext_vector_type(8))) short short8v;
typedef __attribute__((ext_vector_type(4))) float f32x4;
typedef unsigned short ushort_t;
typedef unsigned int uint_t;

__device__ __forceinline__ float sigf(float x) { return 1.0f / (1.0f + expf(-x)); }
// f32 -> bf16 round-to-nearest-even (bit manip, deterministic)
__device__ __forceinline__ ushort_t f2b(float f) {
  uint_t u = __float_as_uint(f);
  uint_t r = (u + 0x7FFFu + ((u >> 16) & 1u)) >> 16;
  return (ushort_t)r;
}
__device__ __forceinline__ float b2f(ushort_t u) {
  return __uint_as_float(((uint_t)u) << 16);
}
__device__ __forceinline__ short8v pack8(float4 a, float4 b) {
  short8v p;
  p[0] = (short)f2b(a.x); p[1] = (short)f2b(a.y);
  p[2] = (short)f2b(a.z); p[3] = (short)f2b(a.w);
  p[4] = (short)f2b(b.x); p[5] = (short)f2b(b.y);
  p[6] = (short)f2b(b.z); p[7] = (short)f2b(b.w);
  return p;
}

#define GLOAD_LDS16(gp, lp)                                                   \
  __builtin_amdgcn_global_load_lds(                                           \
      (const __attribute__((address_space(1))) void*)(gp),                    \
      (__attribute__((address_space(3))) void*)(lp), 16, 0, 0)

// ---------------------------------------------------------------------------
// K1: per-batch top-NKEEP by attention (stable, descending), gather boxes.
__global__ __launch_bounds__(128) void topk_kernel(
    const float* __restrict__ att, const float* __restrict__ boxes,
    int* __restrict__ idx, float* __restrict__ att_sig,
    float* __restrict__ bxk, int* __restrict__ parent) {
  int b = blockIdx.x;
  int t = threadIdx.x;
  __shared__ float a[NOBJ];
  if (t < NOBJ) a[t] = att[b * NOBJ + t];
  __syncthreads();
  if (t < NOBJ) {
    float ai = a[t];
    int rank = 0;
    for (int j = 0; j < NOBJ; j++) {
      float aj = a[j];
      rank += (aj > ai) || (aj == ai && j < t);
    }
    if (rank < NKEEP) {
      idx[b * NKEEP + rank] = t;
      att_sig[b * NKEEP + rank] = 1.0f / (1.0f + expf(-ai));
      for (int c = 0; c < 4; c++)
        bxk[(b * NKEEP + rank) * 4 + c] = boxes[(b * 4 + c) * NOBJ + t];
    }
  }
  if (t < NKEEP) parent[b * NKEEP + t] = NKEEP;  // sentinel
}

// ---------------------------------------------------------------------------
// K2: gather x into A' (fragment-major bf16 [mt][64 ks][g][lane][j]),
// PURE bf16 (round-15: A_lo term dropped; error model round-11-verified).
__global__ __launch_bounds__(256) void gather_x(
    const float* __restrict__ vf, const int* __restrict__ idx,
    ushort_t* __restrict__ A2) {
  int b = blockIdx.x;
  int ksh = blockIdx.y;       // = d0/32, 0..63
  int d0 = ksh * 32;
  __shared__ float s[32][101];
  __shared__ int idxs[NKEEP];
  int tid = threadIdx.x;
  if (tid < NKEEP) idxs[tid] = idx[b * NKEEP + tid];
  for (int l = tid; l < 32 * NOBJ; l += 256) {
    int dd = l / NOBJ, c = l % NOBJ;
    s[dd][c] = vf[((size_t)b * DD + d0 + dd) * NOBJ + c];
  }
  __syncthreads();
  if (tid < NKEEP * 4) {
    int n = tid >> 2, q = tid & 3;   // thread owns 8 contiguous frag shorts
    int m = b * NKEEP + n;
    int mt = m >> 7, r = m & 127, g = r >> 4, row16 = r & 15;
    int cix = idxs[n];
    float v[8];
#pragma unroll
    for (int j = 0; j < 8; ++j) v[j] = s[q * 8 + j][cix];
    float4 va = make_float4(v[0], v[1], v[2], v[3]);
    float4 vb = make_float4(v[4], v[5], v[6], v[7]);
    size_t base = ((size_t)mt * 64 + ksh) * 4096 + g * 512 + (row16 + q * 16) * 8;
    *(short8v*)&A2[base] = pack8(va, vb);
  }
}

// ---------------------------------------------------------------------------
// K3a: f partial sums over a 256-wide d-slice. grid (BB, FDS), 256 thr.
__global__ __launch_bounds__(256) void f_partial(
    const float* __restrict__ vo, const float* __restrict__ Wv,
    const int* __restrict__ idx, float* __restrict__ fpart) {
  int b = blockIdx.x;
  int ds = blockIdx.y;
  int k = threadIdx.x;  // 0..255
  __shared__ int idxs[NKEEP];
  __shared__ float vs[16][NKEEP];
  if (k < NKEEP) idxs[k] = idx[b * NKEEP + k];
  __syncthreads();
  float acc[NKEEP];
#pragma unroll
  for (int n = 0; n < NKEEP; n++) acc[n] = 0.0f;
  int dbeg = ds * (DD / FDS);
  for (int d0 = dbeg; d0 < dbeg + DD / FDS; d0 += 16) {
    __syncthreads();
    for (int l = k; l < 16 * NKEEP; l += 256) {
      int dd = l / NKEEP, n = l % NKEEP;
      vs[dd][n] = vo[((size_t)b * DD + d0 + dd) * NOBJ + idxs[n]];
    }
    __syncthreads();
#pragma unroll
    for (int dd = 0; dd < 16; dd++) {
      float w = Wv[(size_t)(d0 + dd) * KS + k];
#pragma unroll
      for (int n = 0; n < NKEEP; n++) acc[n] += vs[dd][n] * w;
    }
  }
  float* op = &fpart[(((size_t)ds * BB + b) * NKEEP) * KS + k];
#pragma unroll
  for (int n = 0; n < NKEEP; n++) op[n * KS] = acc[n];
}

// K3b: combine 8 partials + box term, tanh -> fmat. grid BB, 256 thr.
__global__ __launch_bounds__(256) void f_combine(
    const float* __restrict__ fpart, const float* __restrict__ Wb,
    const float* __restrict__ bxk, float* __restrict__ fmat) {
  int b = blockIdx.x;
  int k = threadIdx.x;
  for (int n = 0; n < NKEEP; n++) {
    float s = 0.0f;
#pragma unroll
    for (int ds = 0; ds < FDS; ds++)
      s += fpart[(((size_t)ds * BB + b) * NKEEP + n) * KS + k];
#pragma unroll
    for (int c = 0; c < 4; c++) s += bxk[(b * NKEEP + n) * 4 + c] * Wb[c * KS + k];
    fmat[((size_t)b * NKEEP + n) * KS + k] = tanhf(s);
  }
}

// ---------------------------------------------------------------------------
// K4: S[b][i][j] = sigmoid((f_i . f_j)/16) * att_i * att_j   (f64 accum)
__global__ __launch_bounds__(256) void s_kernel(
    const float* __restrict__ fmat, const float* __restrict__ att_sig,
    float* __restrict__ S) {
  int b = blockIdx.x;
  int tid = threadIdx.x;
  __shared__ float fs[NKEEP][KS + 1];
  __shared__ float as[NKEEP];
  for (int l = tid; l < NKEEP * KS; l += 256) {
    int n = l / KS, k = l % KS;
    fs[n][k] = fmat[((size_t)b * NKEEP + n) * KS + k];
  }
  if (tid < NKEEP) as[tid] = att_sig[b * NKEEP + tid];
  __syncthreads();
  for (int p = tid; p < NKEEP * NKEEP; p += 256) {
    int i = p / NKEEP, j = p % NKEEP;
    double acc = 0.0;
    for (int k = 0; k < KS; k++) acc += (double)fs[i][k] * (double)fs[j][k];
    float sc = 1.0f / (1.0f + expf(-(float)(acc * (1.0 / 16.0))));
    S[((size_t)b * NKEEP + i) * NKEEP + j] = sc * as[i] * as[j];
  }
}

// ---------------------------------------------------------------------------
// K5: Prim MST forest, one wave per batch.
__global__ __launch_bounds__(64) void prim_kernel(
    const float* __restrict__ S, int* __restrict__ parent,
    int* __restrict__ order) {
  int b = blockIdx.x;
  int lane = threadIdx.x;
  __shared__ float Ss[NKEEP * NKEEP];
  for (int l = lane; l < NKEEP * NKEEP; l += 64) Ss[l] = S[(size_t)b * NKEEP * NKEEP + l];
  __syncthreads();
  unsigned long long mask = 1ull;  // root = 0 (att sorted desc -> argmax=0)
  if (lane == 0) order[b * NKEEP + 0] = 0;
  for (int step = 1; step < NKEEP; step++) {
    float bv = -1.0f;
    int bk = NKEEP * NKEEP;
    for (int l = lane; l < NKEEP * NKEEP; l += 64) {
      int p = l / NKEEP, c = l % NKEEP;
      if (((mask >> p) & 1ull) && !((mask >> c) & 1ull)) {
        float v = Ss[l];
        if (v > bv || (v == bv && l < bk)) { bv = v; bk = l; }
      }
    }
    for (int off = 32; off > 0; off >>= 1) {
      float ov = __shfl_down(bv, off);
      int ok = __shfl_down(bk, off);
      if (ov > bv || (ov == bv && ok < bk)) { bv = ov; bk = ok; }
    }
    bk = __shfl(bk, 0);
    int p = bk / NKEEP, c = bk % NKEEP;
    mask |= (1ull << c);
    if (lane == 0) {
      parent[b * NKEEP + c] = p;
      order[b * NKEEP + step] = c;
    }
  }
}

// ---------------------------------------------------------------------------
// K6a: build W' fragment-major bf16: [nt:32][ks:64][h:8][lane:64][j:8].
// HI rows only (round-11).
__global__ __launch_bounds__(256) void wconv(
    const float* __restrict__ Wu, const float* __restrict__ Wd,
    ushort_t* __restrict__ B2) {
  int nt = blockIdx.x;   // 0..31
  int ks = blockIdx.y;   // 0..63  (hi only)
  int tid = threadIdx.x;
  const float* W = (nt < 16) ? Wu : Wd;
  int n0 = (nt & 15) * 128;
  int k0 = ks * 32;
  __shared__ float tile[32][129];
  for (int l = tid; l < 32 * 128; l += 256) {
    int kk = l >> 7, c = l & 127;
    tile[kk][c] = W[(size_t)(k0 + kk) * N4H + n0 + c];
  }
  __syncthreads();
  size_t obase = ((size_t)nt * 64 + ks) * 4096 + tid * 16;
  ushort_t ob[16];
#pragma unroll
  for (int u = 0; u < 16; u++) {
    int e = tid * 16 + u;
    int h = e >> 9;
    int lane = (e >> 3) & 63;
    int j = e & 7;
    int c = h * 16 + (lane & 15);
    int kk = (lane >> 4) * 8 + j;
    ob[u] = f2b(tile[kk][c]);
  }
  short8v o0, o1;
#pragma unroll
  for (int u = 0; u < 8; ++u) { o0[u] = (short)ob[u]; o1[u] = (short)ob[u + 8]; }
  *(short8v*)&B2[obase] = o0;
  *(short8v*)&B2[obase + 8] = o1;
}

// ---------------------------------------------------------------------------
// K6b: pack Wh (f32 [512][2048]) into frag-major bf16 [s:16][f:128][lane:64][j:8]
__global__ __launch_bounds__(256) void whpack(
    const float* __restrict__ Wh, ushort_t* __restrict__ Wpk) {
  int s = blockIdx.x;      // 0..15
  int fg = blockIdx.y;     // 0..7
  __shared__ float tile[32][257];
  int tid = threadIdx.x;
  for (int l = tid; l < 32 * 64; l += 256) {
    int row = l >> 6, c4 = (l & 63) * 4;
    float4 v = *(const float4*)&Wh[(size_t)(32 * s + row) * N4H + fg * 256 + c4];
    tile[row][c4] = v.x; tile[row][c4 + 1] = v.y;
    tile[row][c4 + 2] = v.z; tile[row][c4 + 3] = v.w;
  }
  __syncthreads();
#pragma unroll
  for (int it = 0; it < 4; it++) {
    int cid = it * 256 + tid;       // 0..1023
    int ff = cid >> 6, lane = cid & 63;
    int f = fg * 16 + ff;
    int col = ff * 16 + (lane & 15);
    int rbase = (lane >> 4) * 8;
    short8v p;
#pragma unroll
    for (int j = 0; j < 8; j++) p[j] = (short)f2b(tile[rbase + j][col]);
    *(short8v*)&Wpk[(((size_t)s * 128 + f) * 64 + lane) * 8] = p;
  }
}

// ---------------------------------------------------------------------------
// K7: MFMA bf16 GEMM, 128x128 tile, 2-phase double-buffered, incremental
// pointers. PURE bf16 (A_hi * B_hi). K=2048, 64 steps, both operands
// consumed as 64 sequential fragment-major tiles (no wrap).
// Round-13 lesson: keep 128^2 (bigger tiles regress without 8-phase sched).
__global__ __launch_bounds__(256) void mfma_gemm(
    const ushort_t* __restrict__ A2, const ushort_t* __restrict__ B2,
    const float* __restrict__ bu, const float* __restrict__ bd,
    float* __restrict__ Cu, float* __restrict__ Cd) {
  __shared__ __align__(16) ushort_t Asl[2][4096];
  __shared__ __align__(16) ushort_t Bsl[2][4096];
  int bid = blockIdx.x;
  int nt = bid & 31;
  int mt = bid >> 5;
  int tid = threadIdx.x;
  int w = tid >> 6, lane = tid & 63;
  int wr = w >> 1, wc = w & 1;
  f32x4 acc[4][4];
#pragma unroll
  for (int i = 0; i < 4; i++)
#pragma unroll
    for (int j = 0; j < 4; j++) acc[i][j] = (f32x4){0.f, 0.f, 0.f, 0.f};

  const ushort_t* ag =
      A2 + (size_t)mt * 64 * 4096 + (w * 2) * 512 + (size_t)lane * 8;
  const ushort_t* bg =
      B2 + (size_t)nt * 64 * 4096 + (w * 2) * 512 + (size_t)lane * 8;
  ushort_t* as0 = &Asl[0][(w * 2) * 512];
  ushort_t* bs0 = &Bsl[0][(w * 2) * 512];
  ushort_t* as1 = &Asl[1][(w * 2) * 512];
  ushort_t* bs1 = &Bsl[1][(w * 2) * 512];

  GLOAD_LDS16(ag, as0);
  GLOAD_LDS16(ag + 512, as0 + 512);
  GLOAD_LDS16(bg, bs0);
  GLOAD_LDS16(bg + 512, bs0 + 512);
  __syncthreads();
  for (int s = 0; s < 64; ++s) {
    int cur = s & 1;
    if (s < 63) {
      ag += 4096;   // next kstep tile (sequential, no wrap)
      bg += 4096;
      ushort_t* asd = cur ? as0 : as1;
      ushort_t* bsd = cur ? bs0 : bs1;
      GLOAD_LDS16(ag, asd);
      GLOAD_LDS16(ag + 512, asd + 512);
      GLOAD_LDS16(bg, bsd);
      GLOAD_LDS16(bg + 512, bsd + 512);
    }
    short8v a[4], bfr[4];
#pragma unroll
    for (int mi = 0; mi < 4; mi++)
      a[mi] = *(const short8v*)&Asl[cur][(wr * 4 + mi) * 512 + lane * 8];
#pragma unroll
    for (int ni = 0; ni < 4; ni++)
      bfr[ni] = *(const short8v*)&Bsl[cur][(wc * 4 + ni) * 512 + lane * 8];
#pragma unroll
    for (int mi = 0; mi < 4; mi++)
#pragma unroll
      for (int ni = 0; ni < 4; ni++)
        acc[mi][ni] = __builtin_amdgcn_mfma_f32_16x16x32_bf16(
            a[mi], bfr[ni], acc[mi][ni], 0, 0, 0);
    __syncthreads();  // drains vmcnt (next tile staged) + guards buf reuse
  }
  // epilogue: C/D map col=lane&15, row=(lane>>4)*4+reg  [m89-verified]
  int col16 = lane & 15, rq = lane >> 4;
#pragma unroll
  for (int ni = 0; ni < 4; ni++) {
    int nglob = nt * 128 + wc * 64 + ni * 16 + col16;
    const float* bias = (nt < 16) ? bu : bd;
    float* C = (nt < 16) ? Cu : Cd;
    int nn = (nt < 16) ? nglob : nglob - N4H;
    float bv = bias[nn];
#pragma unroll
    for (int mi = 0; mi < 4; mi++) {
#pragma unroll
      for (int r = 0; r < 4; r++) {
        int m = mt * 128 + wr * 64 + mi * 16 + rq * 4 + r;
        C[(size_t)m * N4H + nn] = acc[mi][ni][r] + bv;
      }
    }
  }
}

// ---------------------------------------------------------------------------
// K8: one fused TreeLSTM step (up + dn), 512 blocks x 256 thr (round-6 proven).
__global__ __launch_bounds__(256, 2) void lstm_step(
    int i,
    const float* __restrict__ xWu, const float* __restrict__ xWd,
    const ushort_t* __restrict__ Wpku, const ushort_t* __restrict__ Wpkd,
    const int* __restrict__ order, const int* __restrict__ parent,
    float* __restrict__ hsum, float* __restrict__ csum,
    float* __restrict__ hup, float* __restrict__ hd, float* __restrict__ cd) {
  int bid = blockIdx.x;
  int bt = bid >> 5;
  int pkt = bid & 31;
  bool isdn = pkt >= 16;
  int kt = pkt & 15;
  int t = isdn ? i : (NKEEP - 1 - i);
  const float* xW = isdn ? xWd : xWu;
  const ushort_t* Wpk = isdn ? Wpkd : Wpku;

  __shared__ __align__(16) ushort_t Apk[16 * 64 * 8];  // 16 KB
  __shared__ float pre[16][4][32];                     // 8 KB
  __shared__ int nodes[16], pars[16];

  int tid = threadIdx.x;
  if (tid < 16) {
    int b = bt * 16 + tid;
    int nd = order[b * NKEEP + t];
    nodes[tid] = nd;
    pars[tid] = parent[b * NKEEP + nd];
  }
  __syncthreads();
  // ---- A staging: 16 thr/batch row; thread r covers one s-frag (32 j) ----
  {
    int bl = tid >> 4, r = tid & 15;
    int b = bt * 16 + bl;
    int rowi = isdn ? pars[bl] : nodes[bl];
    const float* asrc = isdn ? &hd[((size_t)b * NP1 + rowi) * H2 + r * 32]
                             : &hsum[((size_t)b * NP1 + rowi) * H2 + r * 32];
    float4 v0 = *(const float4*)&asrc[0];
    float4 v1 = *(const float4*)&asrc[4];
    float4 v2 = *(const float4*)&asrc[8];
    float4 v3 = *(const float4*)&asrc[12];
    float4 v4 = *(const float4*)&asrc[16];
    float4 v5 = *(const float4*)&asrc[20];
    float4 v6 = *(const float4*)&asrc[24];
    float4 v7 = *(const float4*)&asrc[28];
    int x = r & 7;  // XOR swizzle: spreads the r-major stores across banks
    *(short8v*)&Apk[((r * 64 + bl + 0) ^ x) * 8] = pack8(v0, v1);
    *(short8v*)&Apk[((r * 64 + bl + 16) ^ x) * 8] = pack8(v2, v3);
    *(short8v*)&Apk[((r * 64 + bl + 32) ^ x) * 8] = pack8(v4, v5);
    *(short8v*)&Apk[((r * 64 + bl + 48) ^ x) * 8] = pack8(v6, v7);
  }
  __syncthreads();
  // ---- MFMA: wave w = gate; f-pair = g*32 + kt*2 + {0,1} ----
  int w = tid >> 6, lane = tid & 63;
  int col16 = lane & 15, rq = lane >> 4;
  {
    f32x4 acc0 = (f32x4){0.f, 0.f, 0.f, 0.f};
    f32x4 acc1 = (f32x4){0.f, 0.f, 0.f, 0.f};
    int f0 = w * 32 + kt * 2;
#pragma unroll
    for (int s = 0; s < 16; ++s) {
      short8v a = *(const short8v*)&Apk[((s * 64 + lane) ^ (s & 7)) * 8];
      short8v b0 = *(const short8v*)&Wpk[(((size_t)s * 128 + f0) * 64 + lane) * 8];
      short8v b1 = *(const short8v*)&Wpk[(((size_t)s * 128 + f0 + 1) * 64 + lane) * 8];
      acc0 = __builtin_amdgcn_mfma_f32_16x16x32_bf16(a, b0, acc0, 0, 0, 0);
      acc1 = __builtin_amdgcn_mfma_f32_16x16x32_bf16(a, b1, acc1, 0, 0, 0);
    }
#pragma unroll
    for (int r = 0; r < 4; ++r) {
      pre[rq * 4 + r][w][col16] = acc0[r];
      pre[rq * 4 + r][w][16 + col16] = acc1[r];
    }
  }
  __syncthreads();
  // ---- cell epilogue: thread -> (bl, 2 k-cols) ----
  {
    int bl = tid >> 4, kc = (tid & 15) * 2;
    int b = bt * 16 + bl;
    int nd = nodes[bl], pr = pars[bl];
    int k = kt * 32 + kc;
    const float* xwb = &xW[((size_t)b * NKEEP + nd) * N4H + k];
    const float* cpsrc = isdn ? &cd[((size_t)b * NP1 + pr) * H2 + k]
                              : &csum[((size_t)b * NP1 + nd) * H2 + k];
    float2 cp = *(const float2*)cpsrc;
    float hv[2], cv[2];
#pragma unroll
    for (int e = 0; e < 2; ++e) {
      float pi = pre[bl][0][kc + e] + xwb[e];
      float pf = pre[bl][1][kc + e] + xwb[H2 + e];
      float pg = pre[bl][2][kc + e] + xwb[2 * H2 + e];
      float po = pre[bl][3][kc + e] + xwb[3 * H2 + e];
      float cprev = e ? cp.y : cp.x;
      float c = sigf(pi) * tanhf(pg) + sigf(pf) * cprev;
      hv[e] = sigf(po) * tanhf(c);
      cv[e] = c;
    }
    if (!isdn) {
      *(float2*)&hup[((size_t)b * NKEEP + nd) * H2 + k] = make_float2(hv[0], hv[1]);
      float* hsp = &hsum[((size_t)b * NP1 + pr) * H2 + k];
      float* csp = &csum[((size_t)b * NP1 + pr) * H2 + k];
      hsp[0] += hv[0]; hsp[1] += hv[1];
      csp[0] += cv[0]; csp[1] += cv[1];
    } else {
      *(float2*)&hd[((size_t)b * NP1 + nd) * H2 + k] = make_float2(hv[0], hv[1]);
      *(float2*)&cd[((size_t)b * NP1 + nd) * H2 + k] = make_float2(cv[0], cv[1]);
    }
  }
}

// ---------------------------------------------------------------------------
// K9: out[b][q][n] = q<512 ? hup[b][n][q] : hd[b][n][q-512]
__global__ __launch_bounds__(256) void out_transpose(
    const float* __restrict__ hup, const float* __restrict__ hd,
    float* __restrict__ out) {
  int b = blockIdx.x;
  __shared__ float s[NKEEP][65];
  for (int half = 0; half < 2; half++) {
    const float* src = half ? hd : hup;
    int rs = half ? NP1 : NKEEP;
    for (int q0 = 0; q0 < H2; q0 += 64) {
      __syncthreads();
      for (int l = threadIdx.x; l < NKEEP * 64; l += 256) {
        int n = l / 64, qq = l % 64;
        s[n][qq] = src[((size_t)b * rs + n) * H2 + q0 + qq];
      }
      __syncthreads();
      for (int l = threadIdx.x; l < NKEEP * 64; l += 256) {
        int qq = l / NKEEP, n = l % NKEEP;
        out[(size_t)b * (HID * NKEEP) + (half * H2 + q0 + qq) * NKEEP + n] = s[n][qq];
      }
    }
  }
}

// ---------------------------------------------------------------------------
extern "C" void kernel_launch(void* const* d_in, const int* in_sizes, int n_in,
                              void* d_out, int out_size, void* d_ws, size_t ws_size,
                              hipStream_t stream) {
  const float* boxes = (const float*)d_in[0];
  const float* attention = (const float*)d_in[1];
  const float* vf = (const float*)d_in[2];
  const float* vo = (const float*)d_in[3];
  const float* Wv = (const float*)d_in[5];
  const float* Wb = (const float*)d_in[6];
  const float* Wx_up = (const float*)d_in[7];
  const float* Wh_up = (const float*)d_in[8];
  const float* b_up = (const float*)d_in[9];
  const float* Wx_dn = (const float*)d_in[10];
  const float* Wh_dn = (const float*)d_in[11];
  const float* b_dn = (const float*)d_in[12];
  float* out = (float*)d_out;

  char* ws = (char*)d_ws;
  size_t off = 0;
  auto take = [&](size_t bytes) -> char* {
    char* p = ws + off;
    off = (off + bytes + 255) & ~(size_t)255;
    return p;
  };
  int* idx = (int*)take((size_t)BB * NKEEP * 4);
  float* att_sig = (float*)take((size_t)BB * NKEEP * 4);
  float* bxk = (float*)take((size_t)BB * NKEEP * 4 * 4);
  int* parent = (int*)take((size_t)BB * NKEEP * 4);
  int* order = (int*)take((size_t)BB * NKEEP * 4);
  float* fmat = (float*)take((size_t)BB * NKEEP * KS * 4);
  float* S = (float*)take((size_t)BB * NKEEP * NKEEP * 4);
  ushort_t* A2 = (ushort_t*)take((size_t)72 * 64 * 4096 * 2);      // 37.7 MB (hi only)
  ushort_t* B2 = (ushort_t*)take((size_t)32 * 64 * 4096 * 2);      // 16.8 MB (hi only)
  float* xWu = (float*)take((size_t)BB * NKEEP * N4H * 4);
  float* xWd = (float*)take((size_t)BB * NKEEP * N4H * 4);
  float* hsum = (float*)take((size_t)BB * NP1 * H2 * 4);
  float* csum = (float*)take((size_t)BB * NP1 * H2 * 4);
  float* hd = (float*)take((size_t)BB * NP1 * H2 * 4);
  float* cd = (float*)take((size_t)BB * NP1 * H2 * 4);
  ushort_t* Wpku = (ushort_t*)take((size_t)16 * 128 * 64 * 8 * 2);  // 2 MB
  ushort_t* Wpkd = (ushort_t*)take((size_t)16 * 128 * 64 * 8 * 2);
  float* hup = (float*)A2;    // alias: A2 (37.7MB) dead after gemm; hup 18.9MB
  float* fpart = xWd;         // alias: consumed by f_combine before gemm writes

  topk_kernel<<<BB, 128, 0, stream>>>(attention, boxes, idx, att_sig, bxk, parent);
  gather_x<<<dim3(BB, 64), 256, 0, stream>>>(vf, idx, A2);
  f_partial<<<dim3(BB, FDS), 256, 0, stream>>>(vo, Wv, idx, fpart);
  f_combine<<<BB, 256, 0, stream>>>(fpart, Wb, bxk, fmat);
  s_kernel<<<BB, 256, 0, stream>>>(fmat, att_sig, S);
  prim_kernel<<<BB, 64, 0, stream>>>(S, parent, order);

  wconv<<<dim3(32, 64), 256, 0, stream>>>(Wx_up, Wx_dn, B2);
  whpack<<<dim3(16, 8), 256, 0, stream>>>(Wh_up, Wpku);
  whpack<<<dim3(16, 8), 256, 0, stream>>>(Wh_dn, Wpkd);

  mfma_gemm<<<72 * 32, 256, 0, stream>>>(A2, B2, b_up, b_dn, xWu, xWd);

  size_t accb = (size_t)BB * NP1 * H2 * 4;
  hipMemsetAsync(hsum, 0, accb * 4, stream);  // hsum,csum,hd,cd contiguous

  for (int i = 0; i < NKEEP; ++i)
    lstm_step<<<512, 256, 0, stream>>>(i, xWu, xWd, Wpku, Wpkd, order, parent,
                                       hsum, csum, hup, hd, cd);

  out_transpose<<<BB, 256, 0, stream>>>(hup, hd, out);
}